// Round 1
// baseline (579.655 us; speedup 1.0000x reference)
//
#include <hip/hip_runtime.h>

// B-spline basis (Cox-de Boor), degree 3, 256 uniform knots, 252 basis fns.
// Only 4 basis values are nonzero per point -> single-pass streaming write of
// the dense [N][252] f32 output with the 4 values filled in place.

constexpr int NUM_KNOTS = 256;
constexpr int NUM_BASIS = 252;          // NUM_KNOTS - DEGREE - 1
constexpr int CHUNKS    = NUM_BASIS / 4; // 63 float4 chunks per row (1008 B, 16B aligned)

typedef float f4 __attribute__((ext_vector_type(4)));

__global__ __launch_bounds__(256) void bspline_kernel(
    const float* __restrict__ X, const float* __restrict__ knots,
    float* __restrict__ out, unsigned int total)
{
    unsigned int t = blockIdx.x * 256u + threadIdx.x;
    if (t >= total) return;
    unsigned int row = t / CHUNKS;          // compiler magic-mul for /63
    unsigned int c   = t - row * CHUNKS;
    int col0 = (int)c * 4;

    float x    = X[row];
    float k0   = knots[0];
    float kend = knots[NUM_KNOTS - 1];
    float inv_h = (float)(NUM_KNOTS - 1) / (kend - k0);

    // analytic interval estimate + exact fixup against the real knot array
    int j0 = (int)floorf((x - k0) * inv_h);
    j0 = min(max(j0, 0), NUM_KNOTS - 2);
    while (j0 > 0 && x < knots[j0]) --j0;
    while (j0 < NUM_KNOTS - 2 && x >= knots[j0 + 1]) ++j0;

    f4 v = (f4)0.0f;

    // nonzero columns are j0-3 .. j0 (clipped to [0,251] via validity below)
    if (col0 + 3 >= j0 - 3 && col0 <= j0) {
        // cb[i] at level k holds B_{j0-k+i, k}; level 0: B_{j0,0} = 1
        float cb[4] = {1.0f, 0.0f, 0.0f, 0.0f};
        #pragma unroll
        for (int k = 1; k <= 3; ++k) {
            #pragma unroll
            for (int i = 3; i >= 0; --i) {   // downward: in-place update is safe
                if (i > k) continue;
                int j = j0 - k + i;
                float plo = (i >= 1)     ? cb[i - 1] : 0.0f;  // B_{j,   k-1}
                float phi = (i <= k - 1) ? cb[i]     : 0.0f;  // B_{j+1, k-1}
                float val = 0.0f;
                // reference truncation: level-k entries valid for j in [0, 254-k]
                if (j >= 0 && j <= NUM_KNOTS - 2 - k) {
                    float kj  = knots[j];
                    float kj1 = knots[j + 1];
                    float kjk = knots[j + k];
                    float kk1 = knots[j + k + 1];
                    float w1 = (x - kj)  / (kjk - kj);   // uniform knots: denom > 0 always
                    float w2 = (kk1 - x) / (kk1 - kj1);
                    val = w1 * plo + w2 * phi;
                }
                cb[i] = val;
            }
        }
        #pragma unroll
        for (int r = 0; r < 4; ++r) {
            int i = (col0 + r) - (j0 - 3);   // which of the 4 values lands here
            float val = 0.0f;
            if      (i == 0) val = cb[0];
            else if (i == 1) val = cb[1];
            else if (i == 2) val = cb[2];
            else if (i == 3) val = cb[3];
            v[r] = val;
        }
    }

    f4* dst = (f4*)(out + (size_t)row * NUM_BASIS) + c;   // 16B-aligned: 1008 = 63*16
    __builtin_nontemporal_store(v, dst);
}

extern "C" void kernel_launch(void* const* d_in, const int* in_sizes, int n_in,
                              void* d_out, int out_size, void* d_ws, size_t ws_size,
                              hipStream_t stream) {
    const float* x     = (const float*)d_in[0];
    const float* knots = (const float*)d_in[1];
    float* out = (float*)d_out;
    unsigned int n = (unsigned int)in_sizes[0];
    unsigned int total = n * (unsigned int)CHUNKS;
    unsigned int grid = (total + 255u) / 256u;
    bspline_kernel<<<grid, 256, 0, stream>>>(x, knots, out, total);
}

// Round 2
// 213.201 us; speedup vs baseline: 2.7188x; 2.7188x over previous
//
#include <hip/hip_runtime.h>

// B-spline basis (Cox-de Boor), degree 3, 256 knots, 252 basis fns, N=1M.
// Only 4 basis values per row are nonzero. Round-2 structure:
//   phase 1: one thread per row computes (j0, cb[4])  -> LDS   (recursion 1x/row)
//   phase 2: streaming write of 256 rows x 63 float4 chunks, coalesced + NT
// This removes the 63x-replicated divergent recursion that made round 1
// VALU-bound (VALUBusy 88%).

constexpr int NUM_KNOTS = 256;
constexpr int NUM_BASIS = 252;     // NUM_KNOTS - DEGREE - 1
constexpr int CHUNKS    = 63;      // float4 chunks per row (1008 B)
constexpr int ROWS      = 256;     // rows per block == blockDim.x

typedef float f4 __attribute__((ext_vector_type(4)));

__global__ __launch_bounds__(256) void bspline_kernel(
    const float* __restrict__ X, const float* __restrict__ knots,
    float* __restrict__ out, int n)
{
    __shared__ f4  s_cb[ROWS];
    __shared__ int s_j0[ROWS];

    const int tid  = threadIdx.x;
    const int base = blockIdx.x * ROWS;
    const int row  = base + tid;

    // ---------- phase 1: per-row Cox-de Boor (4 nonzero values) ----------
    {
        float x = X[min(row, n - 1)];
        float k0   = knots[0];
        float kend = knots[NUM_KNOTS - 1];
        float inv_h = (float)(NUM_KNOTS - 1) / (kend - k0);

        int j0 = (int)floorf((x - k0) * inv_h);
        j0 = min(max(j0, 0), NUM_KNOTS - 2);
        while (j0 > 0 && x < knots[j0]) --j0;
        while (j0 < NUM_KNOTS - 2 && x >= knots[j0 + 1]) ++j0;

        // cb[i] at level k holds B_{j0-k+i, k}; level 0: B_{j0,0} = 1
        float cb[4] = {1.0f, 0.0f, 0.0f, 0.0f};
        #pragma unroll
        for (int k = 1; k <= 3; ++k) {
            #pragma unroll
            for (int i = 3; i >= 0; --i) {       // downward: in-place safe
                if (i > k) continue;
                int j = j0 - k + i;
                float plo = (i >= 1)     ? cb[i - 1] : 0.0f;  // B_{j,  k-1}
                float phi = (i <= k - 1) ? cb[i]     : 0.0f;  // B_{j+1,k-1}
                float val = 0.0f;
                // reference truncation: level-k entries valid for j in [0, 254-k]
                if (j >= 0 && j <= NUM_KNOTS - 2 - k) {
                    float kj  = knots[j];
                    float kj1 = knots[j + 1];
                    float kjk = knots[j + k];
                    float kk1 = knots[j + k + 1];
                    val = (x - kj) / (kjk - kj) * plo
                        + (kk1 - x) / (kk1 - kj1) * phi;
                }
                cb[i] = val;
            }
        }
        f4 cv; cv.x = cb[0]; cv.y = cb[1]; cv.z = cb[2]; cv.w = cb[3];
        s_cb[tid] = cv;
        s_j0[tid] = j0;
    }
    __syncthreads();

    // ---------- phase 2: stream 256 rows x 63 chunks, coalesced ----------
    // global chunk index i = r*63 + c == flat float4 offset within the block
    int r = tid / CHUNKS;
    int c = tid - r * CHUNKS;
    f4* dst = (f4*)(out + (size_t)base * NUM_BASIS) + tid;
    const bool full = (base + ROWS <= n);   // uniform; true for N=1M

    #pragma unroll 2
    for (int it = 0; it < CHUNKS; ++it) {
        f4  cv = s_cb[r];           // broadcast-ish: <=2 rows per wave
        int j0 = s_j0[r];
        int d  = c * 4 - (j0 - 3);  // band index of this chunk's slot 0
        f4 v;
        #pragma unroll
        for (int rr = 0; rr < 4; ++rr) {
            int e = d + rr;
            float val = 0.0f;
            val = (e == 0) ? cv.x : val;
            val = (e == 1) ? cv.y : val;
            val = (e == 2) ? cv.z : val;
            val = (e == 3) ? cv.w : val;
            v[rr] = val;
        }
        if (full || base + r < n)
            __builtin_nontemporal_store(v, dst);
        dst += 256;
        r += 4; c += 4;
        if (c >= CHUNKS) { c -= CHUNKS; ++r; }   // 256 = 4*63 + 4
    }
}

extern "C" void kernel_launch(void* const* d_in, const int* in_sizes, int n_in,
                              void* d_out, int out_size, void* d_ws, size_t ws_size,
                              hipStream_t stream) {
    const float* x     = (const float*)d_in[0];
    const float* knots = (const float*)d_in[1];
    float* out = (float*)d_out;
    int n = in_sizes[0];
    int grid = (n + ROWS - 1) / ROWS;
    bspline_kernel<<<grid, 256, 0, stream>>>(x, knots, out, n);
}

// Round 3
// 202.811 us; speedup vs baseline: 2.8581x; 1.0512x over previous
//
#include <hip/hip_runtime.h>

// B-spline basis (Cox-de Boor), degree 3, 256 knots, 252 basis fns, N=1M.
// Round-3: phase 1 computes, per row, the (<=2) nonzero float4 chunks
// (c_lo,v_lo),(c_hi,v_hi) -> LDS; phase 2 is a near-pure coalesced write
// stream (2 cmp + 8 cndmask per 16B store). Plain stores (not nontemporal):
// the harness's own fillBuffer hits 6.8 TB/s with plain stores.

constexpr int NUM_KNOTS = 256;
constexpr int NUM_BASIS = 252;     // NUM_KNOTS - DEGREE - 1
constexpr int CHUNKS    = 63;      // float4 chunks per row (1008 B)
constexpr int ROWS      = 256;     // rows per block == blockDim.x

typedef float f4 __attribute__((ext_vector_type(4)));

__global__ __launch_bounds__(256) void bspline_kernel(
    const float* __restrict__ X, const float* __restrict__ knots,
    float* __restrict__ out, int n)
{
    __shared__ float s_knots[NUM_KNOTS];
    __shared__ f4   s_vlo[ROWS];
    __shared__ f4   s_vhi[ROWS];
    __shared__ int2 s_cc[ROWS];

    const int tid  = threadIdx.x;
    const int base = blockIdx.x * ROWS;
    const int row  = base + tid;

    s_knots[tid] = knots[tid];
    __syncthreads();

    // ---------- phase 1: per-row Cox-de Boor -> two nonzero chunks ----------
    {
        float x    = X[min(row, n - 1)];
        float k0   = s_knots[0];
        float kend = s_knots[NUM_KNOTS - 1];
        float inv_h = (float)(NUM_KNOTS - 1) / (kend - k0);

        int j0 = (int)floorf((x - k0) * inv_h);
        j0 = min(max(j0, 0), NUM_KNOTS - 2);
        while (j0 > 0 && x < s_knots[j0]) --j0;
        while (j0 < NUM_KNOTS - 2 && x >= s_knots[j0 + 1]) ++j0;

        // cb[i] at level k holds B_{j0-k+i, k}; level 0: B_{j0,0} = 1
        float cb[4] = {1.0f, 0.0f, 0.0f, 0.0f};
        #pragma unroll
        for (int k = 1; k <= 3; ++k) {
            #pragma unroll
            for (int i = 3; i >= 0; --i) {       // downward: in-place safe
                if (i > k) continue;
                int j = j0 - k + i;
                float plo = (i >= 1)     ? cb[i - 1] : 0.0f;  // B_{j,  k-1}
                float phi = (i <= k - 1) ? cb[i]     : 0.0f;  // B_{j+1,k-1}
                float val = 0.0f;
                // reference truncation: level-k entries valid for j in [0, 254-k]
                if (j >= 0 && j <= NUM_KNOTS - 2 - k) {
                    float kj  = s_knots[j];
                    float kj1 = s_knots[j + 1];
                    float kjk = s_knots[j + k];
                    float kk1 = s_knots[j + k + 1];
                    val = (x - kj) / (kjk - kj) * plo
                        + (kk1 - x) / (kk1 - kj1) * phi;
                }
                cb[i] = val;
            }
        }

        // Band columns j0-3..j0 hold cb[0..3]; they span at most two aligned
        // float4 chunks: c_lo = (j0-3)>>2 (slots a..3) and c_lo+1 (slots 0..a-1),
        // where a = (j0-3)&3. Build both via conditional register shifts
        // (static indices only — rule #20).
        int s = j0 - 3;                  // in [-3, 251]
        int a = s & 3;
        int clo = s >> 2;                // arithmetic shift: -3..-1 -> -1
        float lo0=cb[0], lo1=cb[1], lo2=cb[2], lo3=cb[3];
        float hi0=0.f, hi1=0.f, hi2=0.f, hi3=0.f;
        if (a & 2) { hi3=hi1; hi2=hi0; hi1=lo3; hi0=lo2;
                     lo3=lo1; lo2=lo0; lo1=0.f; lo0=0.f; }
        if (a & 1) { hi3=hi2; hi2=hi1; hi1=hi0; hi0=lo3;
                     lo3=lo2; lo2=lo1; lo1=lo0; lo0=0.f; }
        f4 vlo; vlo.x=lo0; vlo.y=lo1; vlo.z=lo2; vlo.w=lo3;
        f4 vhi; vhi.x=hi0; vhi.y=hi1; vhi.z=hi2; vhi.w=hi3;
        s_vlo[tid] = vlo;
        s_vhi[tid] = vhi;
        s_cc[tid]  = make_int2(clo, clo + 1);
        // clo == -1 (j0<=2): lower spill never matches c in [0,62]; the valid
        // part sits in chunk 0 == clo+1. clo+1 == 63 (j0==254): upper spill
        // dropped; those entries are zero by the truncation guard anyway.
    }
    __syncthreads();

    // ---------- phase 2: stream 256 rows x 63 chunks, coalesced ----------
    int r = tid / CHUNKS;
    int c = tid - r * CHUNKS;
    f4* dst = (f4*)(out + (size_t)base * NUM_BASIS) + tid;
    const bool full = (base + ROWS <= n);   // uniform; true for N=1M

    #pragma unroll 3
    for (int it = 0; it < CHUNKS; ++it) {
        f4   vlo = s_vlo[r];
        f4   vhi = s_vhi[r];
        int2 cc  = s_cc[r];
        bool blo = (c == cc.x);
        bool bhi = (c == cc.y);
        f4 v;
        #pragma unroll
        for (int t = 0; t < 4; ++t)
            v[t] = blo ? vlo[t] : (bhi ? vhi[t] : 0.0f);
        if (full || base + r < n)
            dst[0] = v;                  // plain store — L2 write-combining
        dst += 256;
        r += 4; c += 4;
        if (c >= CHUNKS) { c -= CHUNKS; ++r; }   // 256 = 4*63 + 4
    }
}

extern "C" void kernel_launch(void* const* d_in, const int* in_sizes, int n_in,
                              void* d_out, int out_size, void* d_ws, size_t ws_size,
                              hipStream_t stream) {
    const float* x     = (const float*)d_in[0];
    const float* knots = (const float*)d_in[1];
    float* out = (float*)d_out;
    int n = in_sizes[0];
    int grid = (n + ROWS - 1) / ROWS;
    bspline_kernel<<<grid, 256, 0, stream>>>(x, knots, out, n);
}